// Round 10
// baseline (177.535 us; speedup 1.0000x reference)
//
#include <hip/hip_runtime.h>
#include <hip/hip_bf16.h>
#include <cstdint>
#include <cstddef>

// Problem constants
#define N_NODES 4096
#define F_IN    256
#define H_HEADS 4
#define D_HEAD  64
#define FEAT    256           // H*D
#define SLOPE   0.2f
#define LN_EPS  1e-5f

// Attention tiling
#define NCHUNK  8
#define J_CHUNK 512
#define I_TILE  32
#define K_STEP  32
#define NSTEP   (J_CHUNK / K_STEP)   // 16

typedef __attribute__((ext_vector_type(8))) short bf16x8;
typedef __attribute__((ext_vector_type(4))) float f32x4;

// Workspace layout (bytes).
#define GMAX_OFF   64                                          // float[4][64] tile maxima, 1 KB
#define ADJB_OFF   4096
#define ADJB_BYTES ((size_t)N_NODES * 128 * 4)                 // 2 MB bitmask
#define WXT_OFF    (ADJB_OFF + ADJB_BYTES)
#define WXT_BYTES  ((size_t)FEAT * N_NODES * 2)                // 2 MB bf16, [feat][node]
#define SSRC_OFF   (WXT_OFF + WXT_BYTES)
#define SVEC_BYTES ((size_t)H_HEADS * N_NODES * 4)             // 64 KB planar
#define ETAB_OFF   (SSRC_OFF + SVEC_BYTES)
#define ETAB_BYTES ((size_t)H_HEADS * N_NODES * 8)             // 128 KB float2 {e^s, e^0.2s}
#define WSL_OFF    (ETAB_OFF + ETAB_BYTES)
#define WSL_BYTES  ((size_t)NCHUNK * N_NODES * H_HEADS * 4)    // 512 KB
#define WSACC_OFF  (WSL_OFF + WSL_BYTES)                       // + 33.5 MB

// ---------------------------------------------------------------------------
// helpers
// ---------------------------------------------------------------------------
__device__ __forceinline__ short f2bf(float f) {   // RNE f32 -> bf16 bits
    uint32_t u = __float_as_uint(f);
    uint32_t r = (u + 0x7fffu + ((u >> 16) & 1u)) >> 16;
    return (short)r;
}

// ---------------------------------------------------------------------------
// prep_kernel: blocks [0,512) bit-pack adjacency (4 u32 words / thread, with
// per-block u8-vs-i32 dtype detect); blocks [512,768) run the f32 GEMM
// Wx = x@W^T fused with WxT bf16 transpose-out, s_src planar, ETAB exps,
// and a PLAIN STORE of this tile's s_dst max into gmaxArr[h][nt] (race-free:
// every slot written exactly once; no init, no atomics, no memset).
// ---------------------------------------------------------------------------
__global__ __launch_bounds__(256) void prep_kernel(const void* __restrict__ adjv,
                                                   uint32_t* __restrict__ bits,
                                                   const float* __restrict__ x,
                                                   const float* __restrict__ W,
                                                   const float* __restrict__ a,
                                                   short* __restrict__ WxT,
                                                   float* __restrict__ s_srcT,
                                                   float2* __restrict__ etab,
                                                   float* __restrict__ gmaxArr) {
    __shared__ int   s_u8;
    __shared__ float xs[64][68];
    __shared__ float wsm[64][68];
    __shared__ float aS[64], aD[64];
    __shared__ float wredmax[4];

    const int bid = blockIdx.x;
    const int t   = threadIdx.x;

    if (bid < 512) {
        // ---------------- adjacency pack ----------------
        const int gid4 = (bid * 256 + t) * 4;      // first of 4 words
        uint32_t w8[32];
        const uint32_t* s8 = (const uint32_t*)adjv + (size_t)gid4 * 8;
        uint32_t off = 0;
        #pragma unroll
        for (int k = 0; k < 32; ++k) { w8[k] = s8[k]; off |= w8[k] & 0xFFFFFF00u; }
        if (t == 0) s_u8 = 0;
        __syncthreads();
        if (off) s_u8 = 1;        // benign same-value race
        __syncthreads();

        if (s_u8) {
            #pragma unroll
            for (int w = 0; w < 4; ++w) {
                uint32_t b = 0;
                #pragma unroll
                for (int k = 0; k < 8; ++k) {
                    uint32_t v = w8[w * 8 + k];
                    if (v & 0x000000ffu) b |= 1u << (k * 4 + 0);
                    if (v & 0x0000ff00u) b |= 1u << (k * 4 + 1);
                    if (v & 0x00ff0000u) b |= 1u << (k * 4 + 2);
                    if (v & 0xff000000u) b |= 1u << (k * 4 + 3);
                }
                bits[gid4 + w] = b;
            }
        } else {
            const int4* si = (const int4*)adjv + (size_t)gid4 * 8;
            #pragma unroll
            for (int w = 0; w < 4; ++w) {
                uint32_t b = 0;
                #pragma unroll
                for (int k = 0; k < 8; ++k) {
                    int4 v = si[w * 8 + k];
                    if (v.x) b |= 1u << (k * 4 + 0);
                    if (v.y) b |= 1u << (k * 4 + 1);
                    if (v.z) b |= 1u << (k * 4 + 2);
                    if (v.w) b |= 1u << (k * 4 + 3);
                }
                bits[gid4 + w] = b;
            }
        }
        return;
    }

    // ---------------- GEMM ----------------
    const int h  = (bid - 512) >> 6;   // head
    const int nt = (bid - 512) & 63;   // node tile
    const int tm = t >> 4, tn = t & 15;
    if (t < 64)       aS[t]      = a[h * 128 + t];
    else if (t < 128) aD[t - 64] = a[h * 128 + 64 + (t - 64)];
    float acc[4][4] = {};

    for (int k0 = 0; k0 < F_IN; k0 += 64) {
        #pragma unroll
        for (int s = 0; s < 4; ++s) {
            int idx = t + s * 256;
            int r = idx >> 4, c4 = (idx & 15) << 2;
            *(float4*)&xs[r][c4]  = *(const float4*)&x[(size_t)(nt * 64 + r) * F_IN + k0 + c4];
            *(float4*)&wsm[r][c4] = *(const float4*)&W[(size_t)(h * 64 + r) * F_IN + k0 + c4];
        }
        __syncthreads();
        #pragma unroll 4
        for (int kq = 0; kq < 16; ++kq) {
            float4 xa[4], wb[4];
            #pragma unroll
            for (int mi = 0; mi < 4; ++mi) xa[mi] = *(const float4*)&xs[tm * 4 + mi][kq * 4];
            #pragma unroll
            for (int ni = 0; ni < 4; ++ni) wb[ni] = *(const float4*)&wsm[tn + 16 * ni][kq * 4];
            #pragma unroll
            for (int mi = 0; mi < 4; ++mi)
                #pragma unroll
                for (int ni = 0; ni < 4; ++ni) {
                    acc[mi][ni] = fmaf(xa[mi].x, wb[ni].x, acc[mi][ni]);
                    acc[mi][ni] = fmaf(xa[mi].y, wb[ni].y, acc[mi][ni]);
                    acc[mi][ni] = fmaf(xa[mi].z, wb[ni].z, acc[mi][ni]);
                    acc[mi][ni] = fmaf(xa[mi].w, wb[ni].w, acc[mi][ni]);
                }
        }
        __syncthreads();
    }

    // WxT bf16 transposed write: [feat][node]; this thread's feature o = tn+16ni
    #pragma unroll
    for (int ni = 0; ni < 4; ++ni) {
        short4 sv;
        sv.x = f2bf(acc[0][ni]); sv.y = f2bf(acc[1][ni]);
        sv.z = f2bf(acc[2][ni]); sv.w = f2bf(acc[3][ni]);
        *(short4*)&WxT[(size_t)(h * 64 + tn + 16 * ni) * N_NODES + nt * 64 + tm * 4] = sv;
    }

    // s_src / s_dst partials over this thread's 4 features, reduce over tn
    float ps[4] = {0.f, 0.f, 0.f, 0.f}, pd[4] = {0.f, 0.f, 0.f, 0.f};
    #pragma unroll
    for (int mi = 0; mi < 4; ++mi)
        #pragma unroll
        for (int ni = 0; ni < 4; ++ni) {
            float v = acc[mi][ni];
            ps[mi] = fmaf(v, aS[tn + 16 * ni], ps[mi]);
            pd[mi] = fmaf(v, aD[tn + 16 * ni], pd[mi]);
        }
    #pragma unroll
    for (int o = 1; o < 16; o <<= 1) {
        #pragma unroll
        for (int mi = 0; mi < 4; ++mi) {
            ps[mi] += __shfl_xor(ps[mi], o, 64);
            pd[mi] += __shfl_xor(pd[mi], o, 64);
        }
    }
    float lmax = -INFINITY;
    if (tn == 0) {
        #pragma unroll
        for (int mi = 0; mi < 4; ++mi) {
            int node = nt * 64 + tm * 4 + mi;
            s_srcT[(size_t)h * N_NODES + node] = ps[mi];
            etab[(size_t)h * N_NODES + node] = make_float2(__expf(pd[mi]), __expf(0.2f * pd[mi]));
            lmax = fmaxf(lmax, pd[mi]);
        }
    }
    #pragma unroll
    for (int o = 1; o < 64; o <<= 1) lmax = fmaxf(lmax, __shfl_xor(lmax, o, 64));
    if ((t & 63) == 0) wredmax[t >> 6] = lmax;
    __syncthreads();
    if (t == 0) {
        float m = fmaxf(fmaxf(wredmax[0], wredmax[1]), fmaxf(wredmax[2], wredmax[3]));
        gmaxArr[h * 64 + nt] = m;      // plain store, slot owned by this block
    }
}

// ---------------------------------------------------------------------------
// Attention chunk kernel: 1024 blocks (128 i-tiles x 8 j-chunks) x 512 threads.
// LDS = Bt dbuf 40 KB + adj 2 KB -> 3 blocks/CU (6 waves/SIMD).
// Per-head global max reduced from gmaxArr (64 entries, one wave-wide load +
// shfl tree). ETAB pairs read straight from global (64 B contiguous per
// (wave,q), 16-lane broadcast, L1/L2-resident). Exp-free P, v_perm bf16 pack,
// ones-column denominator, 2-step-ahead register prefetch of B tiles.
// ---------------------------------------------------------------------------
__global__ __launch_bounds__(512, 6) void attn_chunk(const short* __restrict__ WxT,
                                                     const float* __restrict__ s_srcT,
                                                     const float2* __restrict__ etab,
                                                     const uint32_t* __restrict__ adjbits,
                                                     const float* __restrict__ gmaxArr,
                                                     float* __restrict__ ws_l,
                                                     float* __restrict__ ws_acc) {
    __shared__ short    Bt[2][256][40];     // K_STEP=32 elems + pad to 40 (80B rows)
    __shared__ uint32_t adjW[32][17];       // chunk bitmask (16 words/row) + pad

    const int t     = threadIdx.x;
    const int tile  = blockIdx.x >> 3;
    const int chunk = blockIdx.x & 7;
    const int i0    = tile * I_TILE;
    const int jc    = chunk * J_CHUNK;
    const int wave  = t >> 6, lane = t & 63;
    const int h     = wave & 3, mh = wave >> 2;
    const int col   = lane & 15, q = lane >> 4;

    // ---- stage adjacency bits (512 words, one per thread) ----
    adjW[t >> 4][t & 15] = adjbits[(size_t)(i0 + (t >> 4)) * 128 + chunk * 16 + (t & 15)];

    // ---- prologue: tile0 -> Bt[0]; tile1 -> pfB ----
    const int sf = t >> 1, shalf = t & 1;
    const int4* gsrc = (const int4*)(WxT + (size_t)sf * N_NODES + jc);
    int4 pfA0, pfA1, pfB0, pfB1;
    pfA0 = gsrc[shalf * 2 + 0];           pfA1 = gsrc[shalf * 2 + 1];
    pfB0 = gsrc[4 + shalf * 2 + 0];       pfB1 = gsrc[4 + shalf * 2 + 1];
    {
        int4* ld = (int4*)&Bt[0][sf][shalf * 16];
        ld[0] = pfA0; ld[1] = pfA1;
    }
    __syncthreads();

    // ---- per-lane constants ----
    float gv = gmaxArr[h * 64 + lane];           // full row per wave
    #pragma unroll
    for (int o = 1; o < 64; o <<= 1) gv = fmaxf(gv, __shfl_xor(gv, o, 64));
    const float gm  = gv;                        // global unmasked max for head h

    const int   iL  = mh * 16 + col;             // local row (A-frag row = lane&15)
    const int   i   = i0 + iL;
    const float si  = s_srcT[(size_t)h * N_NODES + i];
    const float em0 = si + gm;
    const float mi_ = fmaxf(em0, SLOPE * em0);   // lrelu(si + gmax)
    const float Ai  = __expf(si - mi_);
    const float A2i = __expf(0.2f * si - mi_);
    const float Ti  = __expf(-si);
    const float4* ejg = (const float4*)(etab + (size_t)h * N_NODES);   // 2 pairs / float4

    f32x4 cacc[4], cl;
    #pragma unroll
    for (int n = 0; n < 4; ++n)
        #pragma unroll
        for (int r2 = 0; r2 < 4; ++r2) cacc[n][r2] = 0.f;
    #pragma unroll
    for (int r2 = 0; r2 < 4; ++r2) cl[r2] = 0.f;

    bf16x8 onesf;
    #pragma unroll
    for (int e = 0; e < 8; ++e) onesf[e] = (col == 0) ? (short)0x3F80 : (short)0;

    #pragma unroll 2
    for (int ks = 0; ks < NSTEP; ++ks) {
        const int cur = ks & 1;

        // 1) write tile ks+1 into Bt[cur^1] (source loaded during step ks-1)
        if (ks + 1 < NSTEP) {
            int4* ld = (int4*)&Bt[cur ^ 1][sf][shalf * 16];
            if (cur) { ld[0] = pfA0; ld[1] = pfA1; }
            else     { ld[0] = pfB0; ld[1] = pfB1; }
        }
        // 2) issue loads for tile ks+2
        if (ks + 2 < NSTEP) {
            if (cur) { pfB0 = gsrc[(ks + 2) * 4 + shalf * 2]; pfB1 = gsrc[(ks + 2) * 4 + shalf * 2 + 1]; }
            else     { pfA0 = gsrc[(ks + 2) * 4 + shalf * 2]; pfA1 = gsrc[(ks + 2) * 4 + shalf * 2 + 1]; }
        }

        // 3) A fragment: p for 8 j's (j = jc + ks*32 + q*8 + jj), exp-free.
        //    ETAB pairs from global: 4 float4 = 64 B contiguous, L1-resident.
        uint32_t wq = adjW[iL][ks] >> (q * 8);
        const int fb = (jc + ks * 32 + q * 8) >> 1;
        float4 e4[4];
        e4[0] = ejg[fb]; e4[1] = ejg[fb + 1]; e4[2] = ejg[fb + 2]; e4[3] = ejg[fb + 3];

        union { uint32_t w[4]; bf16x8 v; } apu;
        #pragma unroll
        for (int pp = 0; pp < 4; ++pp) {
            float B0 = e4[pp].x, B20 = e4[pp].y;
            bool pos0 = B0 >= Ti;
            float pv0 = (pos0 ? Ai : A2i) * (pos0 ? B0 : B20);
            pv0 = (wq & (1u << (2 * pp))) ? pv0 : 0.f;
            float B1 = e4[pp].z, B21 = e4[pp].w;
            bool pos1 = B1 >= Ti;
            float pv1 = (pos1 ? Ai : A2i) * (pos1 ? B1 : B21);
            pv1 = (wq & (1u << (2 * pp + 1))) ? pv1 : 0.f;
            apu.w[pp] = __builtin_amdgcn_perm(__float_as_uint(pv1), __float_as_uint(pv0),
                                              0x07060302u);
        }

        // 4) MFMA against 4 d-tiles + ones column
        #pragma unroll
        for (int n = 0; n < 4; ++n) {
            bf16x8 bfr = *(const bf16x8*)&Bt[cur][h * 64 + n * 16 + col][q * 8];
            cacc[n] = __builtin_amdgcn_mfma_f32_16x16x32_bf16(apu.v, bfr, cacc[n], 0, 0, 0);
        }
        cl = __builtin_amdgcn_mfma_f32_16x16x32_bf16(apu.v, onesf, cl, 0, 0, 0);

        __syncthreads();
    }

    // ---- epilogue: C layout col=lane&15, row=(lane>>4)*4+reg ----
    #pragma unroll
    for (int n = 0; n < 4; ++n)
        #pragma unroll
        for (int r = 0; r < 4; ++r) {
            int ii = i0 + mh * 16 + q * 4 + r;
            ws_acc[((size_t)chunk * N_NODES + ii) * FEAT + h * 64 + n * 16 + col] = cacc[n][r];
        }
    if (col == 0) {
        #pragma unroll
        for (int r = 0; r < 4; ++r) {
            int ii = i0 + mh * 16 + q * 4 + r;
            ws_l[((size_t)chunk * N_NODES + ii) * H_HEADS + h] = cl[r];
        }
    }
}

// ---------------------------------------------------------------------------
// Finalize: one wave per row, float4 per lane. No LDS, no barriers.
// grid 1024 x 256 (4 rows/block).
// ---------------------------------------------------------------------------
__global__ __launch_bounds__(256) void finalize_kernel(const float* __restrict__ x,
                                                       const float* __restrict__ gamma,
                                                       const float* __restrict__ beta,
                                                       const float* __restrict__ ws_l,
                                                       const float* __restrict__ ws_acc,
                                                       float* __restrict__ out) {
    const int w    = threadIdx.x >> 6;
    const int lane = threadIdx.x & 63;
    const int i    = blockIdx.x * 4 + w;
    const int h    = lane >> 4;

    float L = 0.f;
    float4 y = make_float4(0.f, 0.f, 0.f, 0.f);
    #pragma unroll
    for (int c = 0; c < NCHUNK; ++c) {
        L += ws_l[((size_t)c * N_NODES + i) * H_HEADS + h];
        float4 v = *(const float4*)&ws_acc[((size_t)c * N_NODES + i) * FEAT + lane * 4];
        y.x += v.x; y.y += v.y; y.z += v.z; y.w += v.w;
    }
    float inv = (L > 0.f) ? (1.f / L) : 0.f;
    float4 xv = *(const float4*)&x[(size_t)i * FEAT + lane * 4];
    y.x = y.x * inv + xv.x; y.y = y.y * inv + xv.y;
    y.z = y.z * inv + xv.z; y.w = y.w * inv + xv.w;

    float s1 = y.x + y.y + y.z + y.w;
    float s2 = y.x * y.x + y.y * y.y + y.z * y.z + y.w * y.w;
    #pragma unroll
    for (int o = 32; o > 0; o >>= 1) {
        s1 += __shfl_xor(s1, o, 64);
        s2 += __shfl_xor(s2, o, 64);
    }
    float mu  = s1 * (1.f / 256.f);
    float var = s2 * (1.f / 256.f) - mu * mu;
    float r = 1.0f / sqrtf(var + LN_EPS);
    float4 g = *(const float4*)&gamma[lane * 4];
    float4 b = *(const float4*)&beta[lane * 4];
    float4 o4;
    o4.x = (y.x - mu) * r * g.x + b.x;
    o4.y = (y.y - mu) * r * g.y + b.y;
    o4.z = (y.z - mu) * r * g.z + b.z;
    o4.w = (y.w - mu) * r * g.w + b.w;
    *(float4*)&out[(size_t)i * FEAT + lane * 4] = o4;
}

// ---------------------------------------------------------------------------
extern "C" void kernel_launch(void* const* d_in, const int* in_sizes, int n_in,
                              void* d_out, int out_size, void* d_ws, size_t ws_size,
                              hipStream_t stream) {
    const float* x     = (const float*)d_in[0];
    const void*  adj   = d_in[1];
    const float* W     = (const float*)d_in[2];
    const float* a     = (const float*)d_in[3];
    const float* gamma = (const float*)d_in[4];
    const float* beta  = (const float*)d_in[5];
    float* out = (float*)d_out;

    char* ws = (char*)d_ws;
    float*    gmaxArr = (float*)(ws + GMAX_OFF);
    uint32_t* adjbits = (uint32_t*)(ws + ADJB_OFF);
    short*    WxT     = (short*)(ws + WXT_OFF);
    float*    s_srcT  = (float*)(ws + SSRC_OFF);
    float2*   etab    = (float2*)(ws + ETAB_OFF);
    float*    ws_l    = (float*)(ws + WSL_OFF);
    float*    ws_acc  = (float*)(ws + WSACC_OFF);

    prep_kernel<<<768, 256, 0, stream>>>(adj, adjbits, x, W, a, WxT, s_srcT, etab, gmaxArr);
    attn_chunk<<<1024, 512, 0, stream>>>(WxT, s_srcT, etab, adjbits, gmaxArr, ws_l, ws_acc);
    finalize_kernel<<<1024, 256, 0, stream>>>(x, gamma, beta, ws_l, ws_acc, out);
}

// Round 11
// 159.781 us; speedup vs baseline: 1.1111x; 1.1111x over previous
//
#include <hip/hip_runtime.h>
#include <hip/hip_bf16.h>
#include <cstdint>
#include <cstddef>

// Problem constants
#define N_NODES 4096
#define F_IN    256
#define H_HEADS 4
#define D_HEAD  64
#define FEAT    256           // H*D
#define SLOPE   0.2f
#define LN_EPS  1e-5f

// Attention tiling — NCHUNK=4: 512 blocks = exactly 2/CU, one residency round.
#define NCHUNK  4
#define J_CHUNK 1024
#define I_TILE  32
#define K_STEP  32
#define NSTEP   (J_CHUNK / K_STEP)   // 32

typedef __attribute__((ext_vector_type(8))) short bf16x8;
typedef __attribute__((ext_vector_type(4))) float f32x4;

// Workspace layout (bytes).
#define GMAX_OFF   64                                          // float[4][64] tile maxima, 1 KB
#define ADJB_OFF   4096
#define ADJB_BYTES ((size_t)N_NODES * 128 * 4)                 // 2 MB bitmask
#define WXT_OFF    (ADJB_OFF + ADJB_BYTES)
#define WXT_BYTES  ((size_t)FEAT * N_NODES * 2)                // 2 MB bf16, [feat][node]
#define SSRC_OFF   (WXT_OFF + WXT_BYTES)
#define SVEC_BYTES ((size_t)H_HEADS * N_NODES * 4)             // 64 KB planar
#define ETAB_OFF   (SSRC_OFF + SVEC_BYTES)
#define ETAB_BYTES ((size_t)H_HEADS * N_NODES * 8)             // 128 KB float2 {e^s, e^0.2s}
#define WSL_OFF    (ETAB_OFF + ETAB_BYTES)
#define WSL_BYTES  ((size_t)NCHUNK * N_NODES * H_HEADS * 4)    // 256 KB
#define WSACC_OFF  (WSL_OFF + WSL_BYTES)                       // + 16.8 MB

// ---------------------------------------------------------------------------
// helpers
// ---------------------------------------------------------------------------
__device__ __forceinline__ short f2bf(float f) {   // RNE f32 -> bf16 bits
    uint32_t u = __float_as_uint(f);
    uint32_t r = (u + 0x7fffu + ((u >> 16) & 1u)) >> 16;
    return (short)r;
}

// ---------------------------------------------------------------------------
// prep_kernel: blocks [0,512) bit-pack adjacency (4 u32 words / thread, with
// per-block u8-vs-i32 dtype detect); blocks [512,768) run the f32 GEMM
// Wx = x@W^T fused with WxT bf16 transpose-out, s_src planar, ETAB exps,
// and a PLAIN STORE of this tile's s_dst max into gmaxArr[h][nt] (race-free:
// every slot written exactly once; no init, no atomics, no memset).
// ---------------------------------------------------------------------------
__global__ __launch_bounds__(256) void prep_kernel(const void* __restrict__ adjv,
                                                   uint32_t* __restrict__ bits,
                                                   const float* __restrict__ x,
                                                   const float* __restrict__ W,
                                                   const float* __restrict__ a,
                                                   short* __restrict__ WxT,
                                                   float* __restrict__ s_srcT,
                                                   float2* __restrict__ etab,
                                                   float* __restrict__ gmaxArr) {
    __shared__ int   s_u8;
    __shared__ float xs[64][68];
    __shared__ float wsm[64][68];
    __shared__ float aS[64], aD[64];
    __shared__ float wredmax[4];

    const int bid = blockIdx.x;
    const int t   = threadIdx.x;

    if (bid < 512) {
        // ---------------- adjacency pack ----------------
        const int gid4 = (bid * 256 + t) * 4;      // first of 4 words
        uint32_t w8[32];
        const uint32_t* s8 = (const uint32_t*)adjv + (size_t)gid4 * 8;
        uint32_t off = 0;
        #pragma unroll
        for (int k = 0; k < 32; ++k) { w8[k] = s8[k]; off |= w8[k] & 0xFFFFFF00u; }
        if (t == 0) s_u8 = 0;
        __syncthreads();
        if (off) s_u8 = 1;        // benign same-value race
        __syncthreads();

        if (s_u8) {
            #pragma unroll
            for (int w = 0; w < 4; ++w) {
                uint32_t b = 0;
                #pragma unroll
                for (int k = 0; k < 8; ++k) {
                    uint32_t v = w8[w * 8 + k];
                    if (v & 0x000000ffu) b |= 1u << (k * 4 + 0);
                    if (v & 0x0000ff00u) b |= 1u << (k * 4 + 1);
                    if (v & 0x00ff0000u) b |= 1u << (k * 4 + 2);
                    if (v & 0xff000000u) b |= 1u << (k * 4 + 3);
                }
                bits[gid4 + w] = b;
            }
        } else {
            const int4* si = (const int4*)adjv + (size_t)gid4 * 8;
            #pragma unroll
            for (int w = 0; w < 4; ++w) {
                uint32_t b = 0;
                #pragma unroll
                for (int k = 0; k < 8; ++k) {
                    int4 v = si[w * 8 + k];
                    if (v.x) b |= 1u << (k * 4 + 0);
                    if (v.y) b |= 1u << (k * 4 + 1);
                    if (v.z) b |= 1u << (k * 4 + 2);
                    if (v.w) b |= 1u << (k * 4 + 3);
                }
                bits[gid4 + w] = b;
            }
        }
        return;
    }

    // ---------------- GEMM ----------------
    const int h  = (bid - 512) >> 6;   // head
    const int nt = (bid - 512) & 63;   // node tile
    const int tm = t >> 4, tn = t & 15;
    if (t < 64)       aS[t]      = a[h * 128 + t];
    else if (t < 128) aD[t - 64] = a[h * 128 + 64 + (t - 64)];
    float acc[4][4] = {};

    for (int k0 = 0; k0 < F_IN; k0 += 64) {
        #pragma unroll
        for (int s = 0; s < 4; ++s) {
            int idx = t + s * 256;
            int r = idx >> 4, c4 = (idx & 15) << 2;
            *(float4*)&xs[r][c4]  = *(const float4*)&x[(size_t)(nt * 64 + r) * F_IN + k0 + c4];
            *(float4*)&wsm[r][c4] = *(const float4*)&W[(size_t)(h * 64 + r) * F_IN + k0 + c4];
        }
        __syncthreads();
        #pragma unroll 4
        for (int kq = 0; kq < 16; ++kq) {
            float4 xa[4], wb[4];
            #pragma unroll
            for (int mi = 0; mi < 4; ++mi) xa[mi] = *(const float4*)&xs[tm * 4 + mi][kq * 4];
            #pragma unroll
            for (int ni = 0; ni < 4; ++ni) wb[ni] = *(const float4*)&wsm[tn + 16 * ni][kq * 4];
            #pragma unroll
            for (int mi = 0; mi < 4; ++mi)
                #pragma unroll
                for (int ni = 0; ni < 4; ++ni) {
                    acc[mi][ni] = fmaf(xa[mi].x, wb[ni].x, acc[mi][ni]);
                    acc[mi][ni] = fmaf(xa[mi].y, wb[ni].y, acc[mi][ni]);
                    acc[mi][ni] = fmaf(xa[mi].z, wb[ni].z, acc[mi][ni]);
                    acc[mi][ni] = fmaf(xa[mi].w, wb[ni].w, acc[mi][ni]);
                }
        }
        __syncthreads();
    }

    // WxT bf16 transposed write: [feat][node]; this thread's feature o = tn+16ni
    #pragma unroll
    for (int ni = 0; ni < 4; ++ni) {
        short4 sv;
        sv.x = f2bf(acc[0][ni]); sv.y = f2bf(acc[1][ni]);
        sv.z = f2bf(acc[2][ni]); sv.w = f2bf(acc[3][ni]);
        *(short4*)&WxT[(size_t)(h * 64 + tn + 16 * ni) * N_NODES + nt * 64 + tm * 4] = sv;
    }

    // s_src / s_dst partials over this thread's 4 features, reduce over tn
    float ps[4] = {0.f, 0.f, 0.f, 0.f}, pd[4] = {0.f, 0.f, 0.f, 0.f};
    #pragma unroll
    for (int mi = 0; mi < 4; ++mi)
        #pragma unroll
        for (int ni = 0; ni < 4; ++ni) {
            float v = acc[mi][ni];
            ps[mi] = fmaf(v, aS[tn + 16 * ni], ps[mi]);
            pd[mi] = fmaf(v, aD[tn + 16 * ni], pd[mi]);
        }
    #pragma unroll
    for (int o = 1; o < 16; o <<= 1) {
        #pragma unroll
        for (int mi = 0; mi < 4; ++mi) {
            ps[mi] += __shfl_xor(ps[mi], o, 64);
            pd[mi] += __shfl_xor(pd[mi], o, 64);
        }
    }
    float lmax = -INFINITY;
    if (tn == 0) {
        #pragma unroll
        for (int mi = 0; mi < 4; ++mi) {
            int node = nt * 64 + tm * 4 + mi;
            s_srcT[(size_t)h * N_NODES + node] = ps[mi];
            etab[(size_t)h * N_NODES + node] = make_float2(__expf(pd[mi]), __expf(0.2f * pd[mi]));
            lmax = fmaxf(lmax, pd[mi]);
        }
    }
    #pragma unroll
    for (int o = 1; o < 64; o <<= 1) lmax = fmaxf(lmax, __shfl_xor(lmax, o, 64));
    if ((t & 63) == 0) wredmax[t >> 6] = lmax;
    __syncthreads();
    if (t == 0) {
        float m = fmaxf(fmaxf(wredmax[0], wredmax[1]), fmaxf(wredmax[2], wredmax[3]));
        gmaxArr[h * 64 + nt] = m;      // plain store, slot owned by this block
    }
}

// ---------------------------------------------------------------------------
// Attention chunk kernel: 512 blocks (128 i-tiles x 4 j-chunks) x 512 threads.
// ROUND-3 STRUCTURE (measured good): EJ staged in LDS so the K-loop consumes
// only LDS/registers — no in-loop global-load consumption, so the compiler's
// vmcnt waits stay at the LDS-write point and the 2-step register prefetch of
// B tiles keeps its full distance (round-9 lesson: in-loop global consumption
// forces vmcnt(0) right after the prefetch issue, collapsing the pipeline).
// Exp-free P, v_perm bf16 pack, ones-column denominator.
// LDS = Bt 40 KB + adjW 4.2 KB + EJ 32 KB = 76 KB -> 2 blocks/CU.
// ---------------------------------------------------------------------------
__global__ __launch_bounds__(512, 4) void attn_chunk(const short* __restrict__ WxT,
                                                     const float* __restrict__ s_srcT,
                                                     const float2* __restrict__ etab,
                                                     const uint32_t* __restrict__ adjbits,
                                                     const float* __restrict__ gmaxArr,
                                                     float* __restrict__ ws_l,
                                                     float* __restrict__ ws_acc) {
    __shared__ short    Bt[2][256][40];     // K_STEP=32 elems + pad to 40 (80B rows)
    __shared__ uint32_t adjW[32][33];       // chunk bitmask, +1 word pad
    __shared__ float    EJ[4 * 2048];       // {e^s, e^.2s} pairs per head, 32 KB

    const int t     = threadIdx.x;
    const int tile  = blockIdx.x >> 2;
    const int chunk = blockIdx.x & 3;
    const int i0    = tile * I_TILE;
    const int jc    = chunk * J_CHUNK;
    const int wave  = t >> 6, lane = t & 63;
    const int h     = wave & 3, mh = wave >> 2;
    const int col   = lane & 15, q = lane >> 4;

    // ---- stage adjacency bits + ETAB slice ----
    for (int s2 = t; s2 < 1024; s2 += 512)
        adjW[s2 >> 5][s2 & 31] =
            adjbits[(size_t)(i0 + (s2 >> 5)) * 128 + chunk * 32 + (s2 & 31)];
    {
        const float4* esrc = (const float4*)etab;   // [h][4096] float2 = [h][2048] float4
        for (int s2 = t; s2 < 2048; s2 += 512) {
            int pl = s2 >> 9, off = s2 & 511;
            *(float4*)&EJ[pl * 2048 + off * 4] = esrc[(size_t)pl * 2048 + (jc >> 1) + off];
        }
    }

    // ---- prologue: tile0 -> Bt[0]; tile1 -> pfB ----
    const int sf = t >> 1, shalf = t & 1;
    const int4* gsrc = (const int4*)(WxT + (size_t)sf * N_NODES + jc);
    int4 pfA0, pfA1, pfB0, pfB1;
    pfA0 = gsrc[shalf * 2 + 0];           pfA1 = gsrc[shalf * 2 + 1];
    pfB0 = gsrc[4 + shalf * 2 + 0];       pfB1 = gsrc[4 + shalf * 2 + 1];
    {
        int4* ld = (int4*)&Bt[0][sf][shalf * 16];
        ld[0] = pfA0; ld[1] = pfA1;
    }
    __syncthreads();

    // ---- per-lane constants ----
    float gv = gmaxArr[h * 64 + lane];           // 64 tile maxima for head h
    #pragma unroll
    for (int o = 1; o < 64; o <<= 1) gv = fmaxf(gv, __shfl_xor(gv, o, 64));
    const float gm  = gv;                        // global unmasked max for head h

    const int   iL  = mh * 16 + col;             // local row (A-frag row = lane&15)
    const int   i   = i0 + iL;
    const float si  = s_srcT[(size_t)h * N_NODES + i];
    const float em0 = si + gm;
    const float mi_ = fmaxf(em0, SLOPE * em0);   // lrelu(si + gmax)
    const float Ai  = __expf(si - mi_);
    const float A2i = __expf(0.2f * si - mi_);
    const float Ti  = __expf(-si);

    f32x4 cacc[4], cl;
    #pragma unroll
    for (int n = 0; n < 4; ++n)
        #pragma unroll
        for (int r2 = 0; r2 < 4; ++r2) cacc[n][r2] = 0.f;
    #pragma unroll
    for (int r2 = 0; r2 < 4; ++r2) cl[r2] = 0.f;

    bf16x8 onesf;
    #pragma unroll
    for (int e = 0; e < 8; ++e) onesf[e] = (col == 0) ? (short)0x3F80 : (short)0;

    #pragma unroll 2
    for (int ks = 0; ks < NSTEP; ++ks) {
        const int cur = ks & 1;

        // 1) write tile ks+1 into Bt[cur^1] (source loaded during step ks-1)
        if (ks + 1 < NSTEP) {
            int4* ld = (int4*)&Bt[cur ^ 1][sf][shalf * 16];
            if (cur) { ld[0] = pfA0; ld[1] = pfA1; }
            else     { ld[0] = pfB0; ld[1] = pfB1; }
        }
        // 2) issue loads for tile ks+2
        if (ks + 2 < NSTEP) {
            if (cur) { pfB0 = gsrc[(ks + 2) * 4 + shalf * 2]; pfB1 = gsrc[(ks + 2) * 4 + shalf * 2 + 1]; }
            else     { pfA0 = gsrc[(ks + 2) * 4 + shalf * 2]; pfA1 = gsrc[(ks + 2) * 4 + shalf * 2 + 1]; }
        }

        // 3) A fragment: p for 8 j's (j = ks*32 + q*8 + jj), exp-free, LDS-fed
        uint32_t wq = adjW[iL][ks] >> (q * 8);
        float ej[16];
        {
            const float* eb = &EJ[h * 2048 + (ks * 32 + q * 8) * 2];
            *(float4*)&ej[0]  = *(const float4*)&eb[0];
            *(float4*)&ej[4]  = *(const float4*)&eb[4];
            *(float4*)&ej[8]  = *(const float4*)&eb[8];
            *(float4*)&ej[12] = *(const float4*)&eb[12];
        }
        union { uint32_t w[4]; bf16x8 v; } apu;
        #pragma unroll
        for (int pp = 0; pp < 4; ++pp) {
            float B0 = ej[4 * pp + 0], B20 = ej[4 * pp + 1];
            bool pos0 = B0 >= Ti;
            float pv0 = (pos0 ? Ai : A2i) * (pos0 ? B0 : B20);
            pv0 = (wq & (1u << (2 * pp))) ? pv0 : 0.f;
            float B1 = ej[4 * pp + 2], B21 = ej[4 * pp + 3];
            bool pos1 = B1 >= Ti;
            float pv1 = (pos1 ? Ai : A2i) * (pos1 ? B1 : B21);
            pv1 = (wq & (1u << (2 * pp + 1))) ? pv1 : 0.f;
            apu.w[pp] = __builtin_amdgcn_perm(__float_as_uint(pv1), __float_as_uint(pv0),
                                              0x07060302u);
        }

        // 4) MFMA against 4 d-tiles + ones column
        #pragma unroll
        for (int n = 0; n < 4; ++n) {
            bf16x8 bfr = *(const bf16x8*)&Bt[cur][h * 64 + n * 16 + col][q * 8];
            cacc[n] = __builtin_amdgcn_mfma_f32_16x16x32_bf16(apu.v, bfr, cacc[n], 0, 0, 0);
        }
        cl = __builtin_amdgcn_mfma_f32_16x16x32_bf16(apu.v, onesf, cl, 0, 0, 0);

        __syncthreads();
    }

    // ---- epilogue: C layout col=lane&15, row=(lane>>4)*4+reg ----
    #pragma unroll
    for (int n = 0; n < 4; ++n)
        #pragma unroll
        for (int r = 0; r < 4; ++r) {
            int ii = i0 + mh * 16 + q * 4 + r;
            ws_acc[((size_t)chunk * N_NODES + ii) * FEAT + h * 64 + n * 16 + col] = cacc[n][r];
        }
    if (col == 0) {
        #pragma unroll
        for (int r = 0; r < 4; ++r) {
            int ii = i0 + mh * 16 + q * 4 + r;
            ws_l[((size_t)chunk * N_NODES + ii) * H_HEADS + h] = cl[r];
        }
    }
}

// ---------------------------------------------------------------------------
// Finalize: one wave per row, float4 per lane. No LDS, no barriers.
// grid 1024 x 256 (4 rows/block).
// ---------------------------------------------------------------------------
__global__ __launch_bounds__(256) void finalize_kernel(const float* __restrict__ x,
                                                       const float* __restrict__ gamma,
                                                       const float* __restrict__ beta,
                                                       const float* __restrict__ ws_l,
                                                       const float* __restrict__ ws_acc,
                                                       float* __restrict__ out) {
    const int w    = threadIdx.x >> 6;
    const int lane = threadIdx.x & 63;
    const int i    = blockIdx.x * 4 + w;
    const int h    = lane >> 4;

    float L = 0.f;
    float4 y = make_float4(0.f, 0.f, 0.f, 0.f);
    #pragma unroll
    for (int c = 0; c < NCHUNK; ++c) {
        L += ws_l[((size_t)c * N_NODES + i) * H_HEADS + h];
        float4 v = *(const float4*)&ws_acc[((size_t)c * N_NODES + i) * FEAT + lane * 4];
        y.x += v.x; y.y += v.y; y.z += v.z; y.w += v.w;
    }
    float inv = (L > 0.f) ? (1.f / L) : 0.f;
    float4 xv = *(const float4*)&x[(size_t)i * FEAT + lane * 4];
    y.x = y.x * inv + xv.x; y.y = y.y * inv + xv.y;
    y.z = y.z * inv + xv.z; y.w = y.w * inv + xv.w;

    float s1 = y.x + y.y + y.z + y.w;
    float s2 = y.x * y.x + y.y * y.y + y.z * y.z + y.w * y.w;
    #pragma unroll
    for (int o = 32; o > 0; o >>= 1) {
        s1 += __shfl_xor(s1, o, 64);
        s2 += __shfl_xor(s2, o, 64);
    }
    float mu  = s1 * (1.f / 256.f);
    float var = s2 * (1.f / 256.f) - mu * mu;
    float r = 1.0f / sqrtf(var + LN_EPS);
    float4 g = *(const float4*)&gamma[lane * 4];
    float4 b = *(const float4*)&beta[lane * 4];
    float4 o4;
    o4.x = (y.x - mu) * r * g.x + b.x;
    o4.y = (y.y - mu) * r * g.y + b.y;
    o4.z = (y.z - mu) * r * g.z + b.z;
    o4.w = (y.w - mu) * r * g.w + b.w;
    *(float4*)&out[(size_t)i * FEAT + lane * 4] = o4;
}

// ---------------------------------------------------------------------------
extern "C" void kernel_launch(void* const* d_in, const int* in_sizes, int n_in,
                              void* d_out, int out_size, void* d_ws, size_t ws_size,
                              hipStream_t stream) {
    const float* x     = (const float*)d_in[0];
    const void*  adj   = d_in[1];
    const float* W     = (const float*)d_in[2];
    const float* a     = (const float*)d_in[3];
    const float* gamma = (const float*)d_in[4];
    const float* beta  = (const float*)d_in[5];
    float* out = (float*)d_out;

    char* ws = (char*)d_ws;
    float*    gmaxArr = (float*)(ws + GMAX_OFF);
    uint32_t* adjbits = (uint32_t*)(ws + ADJB_OFF);
    short*    WxT     = (short*)(ws + WXT_OFF);
    float*    s_srcT  = (float*)(ws + SSRC_OFF);
    float2*   etab    = (float2*)(ws + ETAB_OFF);
    float*    ws_l    = (float*)(ws + WSL_OFF);
    float*    ws_acc  = (float*)(ws + WSACC_OFF);

    prep_kernel<<<768, 256, 0, stream>>>(adj, adjbits, x, W, a, WxT, s_srcT, etab, gmaxArr);
    attn_chunk<<<512, 512, 0, stream>>>(WxT, s_srcT, etab, adjbits, gmaxArr, ws_l, ws_acc);
    finalize_kernel<<<1024, 256, 0, stream>>>(x, gamma, beta, ws_l, ws_acc, out);
}